// Round 6
// baseline (264.468 us; speedup 1.0000x reference)
//
#include <hip/hip_runtime.h>
#include <stdint.h>

#define A 15
#define H_ 34
#define W_ 34
#define HW (H_*W_)
#define N (A*HW)            // 17340
#define MAX_CAND 3000
#define TOP_N 300
#define NWORDS 47           // ceil(3000/64)
#define CHUNK_W 3008        // 64 rows * 47 words per chunk
#define HB 13               // histogram bits (top of key)
#define HSIZE 8192
#define NB 48               // persistent blocks (<= 256 CUs -> co-resident)
#define BT 1024

__constant__ float c_aw[A] = {9.232984f, 16.0f, 27.712813f, 18.465969f, 32.0f, 55.425626f,
                              36.931937f, 64.0f, 110.851252f, 73.863875f, 128.0f, 221.702503f,
                              147.72775f, 256.0f, 443.405007f};
__constant__ float c_ah[A] = {27.72668f, 16.0f, 9.237604f, 55.453359f, 32.0f, 18.475209f,
                              110.906719f, 64.0f, 36.950417f, 221.813438f, 128.0f, 73.900834f,
                              443.626876f, 256.0f, 147.801669f};

// grid barrier: monotonic arrival counter; release-fence before arrive,
// acquire spin + block-wide L1 invalidate after. All NB blocks co-resident.
__device__ __forceinline__ void gsync(int* bar, int target) {
    __syncthreads();
    if (threadIdx.x == 0) {
        __threadfence();
        __hip_atomic_fetch_add(bar, 1, __ATOMIC_ACQ_REL, __HIP_MEMORY_SCOPE_AGENT);
        while (__hip_atomic_load(bar, __ATOMIC_ACQUIRE, __HIP_MEMORY_SCOPE_AGENT) < target)
            __builtin_amdgcn_s_sleep(8);
    }
    __syncthreads();
    __threadfence();   // every thread: refresh L1 view of other blocks' writes
}

__global__ __launch_bounds__(BT) void k_all(
    const float* __restrict__ cls, const float* __restrict__ pred,
    const int* __restrict__ iminfo,
    int* hist, int* bar, int* control,
    float4* boxes, float2* scores, unsigned long long* keys,
    unsigned long long* skeys, int* sidx,
    float4* cboxes, float2* cscores,
    unsigned long long* kpm, unsigned long long* sup,
    float* out)
{
    __shared__ unsigned long long s_buf[2][CHUNK_W];   // 47 KB, aliased per phase
    __shared__ unsigned long long s_kp[NWORDS];
    __shared__ int s_sel[TOP_N];
    __shared__ int s_misc[4];

    const int tid  = threadIdx.x;
    const int bid  = blockIdx.x;
    const int gtid = bid * BT + tid;

    // ---------------- P1: decode + local histogram ----------------
    int* lhist = (int*)s_buf;
    for (int k = tid; k < HSIZE; k += BT) lhist[k] = 0;
    if (gtid < TOP_N * 7) out[gtid] = 0.0f;
    if (gtid < NWORDS)    kpm[gtid] = 0ull;
    __syncthreads();

    unsigned long long mykey_p1 = 0ull;
    const int m = gtid;
    if (m < N) {
        int a  = m % A;
        int hw = m / A;
        int w  = hw % W_;
        int h  = hw / W_;

        float ow = (float)iminfo[1];
        float oh = (float)iminfo[0];

        float aw = c_aw[a], ah = c_ah[a];
        float xm = __fmul_rn(-0.5f, __fsub_rn(aw, 1.0f));
        float ym = __fmul_rn(-0.5f, __fsub_rn(ah, 1.0f));
        float sxw = (float)(w * 8);
        float syh = (float)(h * 8);
        float x1 = __fadd_rn(sxw, xm);
        float y1 = __fadd_rn(syh, ym);
        float x2 = __fadd_rn(sxw, -xm);
        float y2 = __fadd_rn(syh, -ym);

        float widths  = __fadd_rn(__fsub_rn(x2, x1), 1.0f);
        float heights = __fadd_rn(__fsub_rn(y2, y1), 1.0f);
        float ctr_x = __fadd_rn(x1, __fmul_rn(0.5f, __fsub_rn(widths, 1.0f)));
        float ctr_y = __fadd_rn(y1, __fmul_rn(0.5f, __fsub_rn(heights, 1.0f)));

        const float std0 = 0.12677f,   std1 = 0.095741f, std2 = 0.3173f,    std3 = 0.281042f;
        const float mu0  = 0.000437f,  mu1  = 0.002586f, mu2  = -0.123953f, mu3  = -0.081469f;
        int pb = a * 4 * HW + hw;
        float d0 = __fadd_rn(__fmul_rn(pred[pb + 0 * HW], std0), mu0);
        float d1 = __fadd_rn(__fmul_rn(pred[pb + 1 * HW], std1), mu1);
        float d2 = __fadd_rn(__fmul_rn(pred[pb + 2 * HW], std2), mu2);
        float d3 = __fadd_rn(__fmul_rn(pred[pb + 3 * HW], std3), mu3);

        float pcx = __fadd_rn(__fmul_rn(d0, widths),  ctr_x);
        float pcy = __fadd_rn(__fmul_rn(d1, heights), ctr_y);
        float pw  = __fmul_rn(expf(d2), widths);
        float ph  = __fmul_rn(expf(d3), heights);

        float hpw = __fmul_rn(0.5f, __fsub_rn(pw, 1.0f));
        float hph = __fmul_rn(0.5f, __fsub_rn(ph, 1.0f));
        float bx1 = __fsub_rn(pcx, hpw);
        float by1 = __fsub_rn(pcy, hph);
        float bx2 = __fadd_rn(pcx, hpw);
        float by2 = __fadd_rn(pcy, hph);

        float ow1 = __fsub_rn(ow, 1.0f), oh1 = __fsub_rn(oh, 1.0f);
        bx1 = fminf(fmaxf(bx1, 0.0f), ow1);
        by1 = fminf(fmaxf(by1, 0.0f), oh1);
        bx2 = fminf(fmaxf(bx2, 0.0f), ow1);
        by2 = fminf(fmaxf(by2, 0.0f), oh1);

        float s0 = cls[a * HW + hw];
        float s1 = cls[(A + a) * HW + hw];

        float wsv = __fadd_rn(__fsub_rn(bx2, bx1), 1.0f);
        float hsv = __fadd_rn(__fsub_rn(by2, by1), 1.0f);
        bool keep = (s1 > 0.2f) && ((wsv >= 6.16056f) || (hsv >= 6.16056f));
        float masked = keep ? s1 : -1e30f;

        boxes[m]  = make_float4(bx1, by1, bx2, by2);
        scores[m] = make_float2(s0, s1);

        unsigned int fb = __float_as_uint(masked);
        fb = (fb & 0x80000000u) ? ~fb : (fb | 0x80000000u);
        mykey_p1 = ((unsigned long long)fb << 32) | (unsigned int)(~(unsigned int)m);
        keys[m] = mykey_p1;
        atomicAdd(&lhist[(int)(mykey_p1 >> (64 - HB))], 1);
    }
    __syncthreads();
    for (int k = tid; k < HSIZE; k += BT) {
        int v = lhist[k];
        if (v) atomicAdd(&hist[k], v);
    }
    gsync(bar, NB * 1);

    // ---------------- P2: per-block redundant threshold-bucket scan --------
    int* tsum = (int*)s_buf;
    {
        const int4* h4 = (const int4*)hist;
        int4 va = h4[tid * 2], vb = h4[tid * 2 + 1];
        tsum[tid] = va.x + va.y + va.z + va.w + vb.x + vb.y + vb.z + vb.w;
        __syncthreads();
        for (int d = 1; d < BT; d <<= 1) {
            int v = (tid + d < BT) ? tsum[tid + d] : 0;
            __syncthreads();
            tsum[tid] += v;
            __syncthreads();
        }
        int suf_self = tsum[tid];
        int suf_next = (tid < BT - 1) ? tsum[tid + 1] : 0;
        if (suf_self >= MAX_CAND && suf_next < MAX_CAND) {
            int acc = suf_next, B = tid * 8;
            const int* hh = hist + tid * 8;
            for (int q = 7; q >= 0; --q) {
                acc += hh[q];
                if (acc >= MAX_CAND) { B = tid * 8 + q; break; }
            }
            s_misc[1] = B;
        }
        __syncthreads();
    }
    const int B = s_misc[1];

    // ---------------- P3: compact subset {bucket >= B} ----------------
    if (m < N) {
        if ((int)(mykey_p1 >> (64 - HB)) >= B) {
            int slot = atomicAdd(&control[0], 1);
            skeys[slot] = mykey_p1;
            sidx[slot]  = m;
        }
    }
    gsync(bar, NB * 2);
    const int S = __hip_atomic_load(control, __ATOMIC_ACQUIRE, __HIP_MEMORY_SCOPE_AGENT);

    // ---------------- P4: rank within subset + scatter ----------------
    {
        int* pc = (int*)s_buf;
        const int js = __builtin_amdgcn_readfirstlane(tid >> 8);  // 4 j-slices
        const int il = tid & 255;
        for (int ib = bid; ib * 256 < S; ib += NB) {
            int i = ib * 256 + il;
            unsigned long long mk = (i < S) ? skeys[i] : ~0ull;
            int jlen = (S + 3) >> 2;
            int j0 = js * jlen;
            int j1 = min(j0 + jlen, S);
            int cnt = 0;
            int j = j0;
            for (; j + 8 <= j1; j += 8) {
                #pragma unroll
                for (int u = 0; u < 8; ++u) cnt += (skeys[j + u] > mk) ? 1 : 0;
            }
            for (; j < j1; ++j) cnt += (skeys[j] > mk) ? 1 : 0;
            pc[js * 256 + il] = cnt;
            __syncthreads();
            if (tid < 256) {
                int i2 = ib * 256 + tid;
                if (i2 < S) {
                    int rank = pc[tid] + pc[256 + tid] + pc[512 + tid] + pc[768 + tid];
                    if (rank < MAX_CAND) {
                        int orig = sidx[i2];
                        unsigned long long kk = skeys[i2];
                        cboxes[rank]  = boxes[orig];
                        cscores[rank] = scores[orig];
                        unsigned int fb = (unsigned int)(kk >> 32);
                        float masked = (fb & 0x80000000u) ? __uint_as_float(fb & 0x7fffffffu)
                                                          : __uint_as_float(~fb);
                        if (masked > (-1e30f * 0.5f))
                            atomicOr(&kpm[rank >> 6], 1ull << (rank & 63));
                    }
                }
            }
            __syncthreads();
        }
    }
    gsync(bar, NB * 3);

    // ---------------- P5: IoU suppression bitmask ----------------
    {
        const int lane = tid & 63;
        const int gw = __builtin_amdgcn_readfirstlane((bid << 4) | (tid >> 6));
        for (int t = gw; t < NWORDS * NWORDS; t += NB * 16) {
            int rg = t / NWORDS;
            int w  = t - rg * NWORDS;
            int i  = rg * 64 + lane;
            bool vi = (i < MAX_CAND);
            float4 bi = vi ? cboxes[i] : make_float4(0.f, 0.f, 0.f, 0.f);
            float area_i = __fmul_rn(__fsub_rn(bi.z, bi.x), __fsub_rn(bi.w, bi.y));
            unsigned long long msk = 0ull;
            int jbase = w * 64;
            int jmax  = min(64, MAX_CAND - jbase);
            for (int jj = 0; jj < jmax; ++jj) {
                int j = jbase + jj;              // wave-uniform
                float4 bj = cboxes[j];
                float iw = fmaxf(__fsub_rn(fminf(bi.z, bj.z), fmaxf(bi.x, bj.x)), 0.0f);
                float ih = fmaxf(__fsub_rn(fminf(bi.w, bj.w), fmaxf(bi.y, bj.y)), 0.0f);
                float inter  = __fmul_rn(iw, ih);
                float area_j = __fmul_rn(__fsub_rn(bj.z, bj.x), __fsub_rn(bj.w, bj.y));
                float denom  = fmaxf(__fsub_rn(__fadd_rn(area_i, area_j), inter), 1e-12f);
                bool p = vi && (j > i) && ((inter / denom) > 0.7f);
                msk |= p ? (1ull << jj) : 0ull;
            }
            if (vi) sup[(size_t)i * NWORDS + w] = msk;
        }
    }
    gsync(bar, NB * 4);

    // ---------------- P6: block 0 = chunked greedy NMS + output ----------
    if (bid != 0) return;

    unsigned long long (*buf)[CHUNK_W] = s_buf;
    for (int t = tid; t < TOP_N; t += BT) s_sel[t] = -1;
    if (tid < NWORDS) s_kp[tid] = kpm[tid];

    {
        unsigned long long v0 = sup[tid];
        unsigned long long v1 = sup[tid + 1024];
        unsigned long long v2 = (tid + 2048 < CHUNK_W) ? sup[tid + 2048] : 0ull;
        buf[0][tid] = v0;
        buf[0][tid + 1024] = v1;
        if (tid + 2048 < CHUNK_W) buf[0][tid + 2048] = v2;
    }
    __syncthreads();

    const int lane = tid & 63;
    const int wave = tid >> 6;
    int kept_total = 0;
    for (int w = 0; w < NWORDS; ++w) {
        int cur = w & 1;
        bool havnext = (w + 1 < NWORDS);

        unsigned long long v0 = 0, v1 = 0, v2 = 0;
        if (havnext) {
            const unsigned long long* src = sup + (size_t)(w + 1) * CHUNK_W;
            v0 = src[tid];
            v1 = src[tid + 1024];
            v2 = (tid + 2048 < CHUNK_W) ? src[tid + 2048] : 0ull;
        }

        if (wave == 0) {
            unsigned long long intra = buf[cur][lane * NWORDS + w];
            unsigned long long nz = __ballot(intra != 0ull);
            unsigned long long kw = s_kp[w];
            unsigned long long rem = kw & nz;
            while (rem) {
                int b = __ffsll((long long)rem) - 1;
                rem &= rem - 1;
                if ((kw >> b) & 1ull) {
                    unsigned long long row = __shfl(intra, b, 64);
                    kw  &= ~row;
                    rem &= ~row;
                }
            }
            if (lane == 0) s_kp[w] = kw;
            kept_total += __popcll(kw);
            bool stop = (kept_total >= TOP_N) || !havnext;
            if (lane == 0) s_misc[0] = stop ? 1 : 0;

            if (!stop && lane < NWORDS && lane > w) {
                unsigned long long comb = 0;
                #pragma unroll 8
                for (int b = 0; b < 64; ++b) {
                    unsigned long long r = buf[cur][b * NWORDS + lane];
                    if ((kw >> b) & 1ull) comb |= r;
                }
                s_kp[lane] &= ~comb;
            }
        }

        if (havnext) {
            int nxt = cur ^ 1;
            buf[nxt][tid] = v0;
            buf[nxt][tid + 1024] = v1;
            if (tid + 2048 < CHUNK_W) buf[nxt][tid + 2048] = v2;
        }
        __syncthreads();
        if (s_misc[0]) break;
    }

    if (wave == 0) {
        unsigned long long kw = (lane < NWORDS) ? s_kp[lane] : 0ull;
        int cnt = __popcll(kw);
        int pre = cnt;
        for (int d = 1; d < 64; d <<= 1) {
            int o = __shfl_up(pre, d, 64);
            if (lane >= d) pre += o;
        }
        int prefix = pre - cnt;
        while (kw && prefix < TOP_N) {
            int b = __ffsll((long long)kw) - 1;
            kw &= kw - 1;
            s_sel[prefix] = lane * 64 + b;
            prefix++;
        }
    }
    __syncthreads();

    if (tid < TOP_N) {
        int j = s_sel[tid];
        if (j >= 0) {
            float4 bx = cboxes[j];
            float2 sc = cscores[j];
            out[tid * 5 + 0] = 0.0f;
            out[tid * 5 + 1] = bx.x;
            out[tid * 5 + 2] = bx.y;
            out[tid * 5 + 3] = bx.z;
            out[tid * 5 + 4] = bx.w;
            out[TOP_N * 5 + tid * 2 + 0] = sc.x;
            out[TOP_N * 5 + tid * 2 + 1] = sc.y;
        }
    }
}

// ---------------------------------------------------------------------------
extern "C" void kernel_launch(void* const* d_in, const int* in_sizes, int n_in,
                              void* d_out, int out_size, void* d_ws, size_t ws_size,
                              hipStream_t stream) {
    const float* cls    = (const float*)d_in[0];
    const float* pred   = (const float*)d_in[1];
    const int*   iminfo = (const int*)d_in[2];
    float* out = (float*)d_out;

    char* p = (char*)d_ws;
    auto alloc = [&](size_t bytes) -> char* {
        char* q = p;
        p += (bytes + 255) & ~(size_t)255;
        return q;
    };
    // hist + bar/control contiguous -> one memset
    int* hist     = (int*)alloc((size_t)HSIZE * 4);   // 32768 B (256-aligned)
    int* barctrl  = (int*)alloc(256);                  // [0]=bar, [1]=S-counter
    float4* boxes  = (float4*)alloc((size_t)N * sizeof(float4));
    float2* scores = (float2*)alloc((size_t)N * sizeof(float2));
    unsigned long long* keys  = (unsigned long long*)alloc((size_t)N * 8);
    unsigned long long* skeys = (unsigned long long*)alloc((size_t)N * 8);
    int* sidx = (int*)alloc((size_t)N * 4);
    float4* cboxes  = (float4*)alloc((size_t)MAX_CAND * sizeof(float4));
    float2* cscores = (float2*)alloc((size_t)MAX_CAND * sizeof(float2));
    unsigned long long* kpm = (unsigned long long*)alloc((size_t)NWORDS * 8);
    unsigned long long* sup = (unsigned long long*)alloc((size_t)MAX_CAND * NWORDS * 8);

    hipMemsetAsync(hist, 0, (size_t)HSIZE * 4 + 256, stream);
    k_all<<<NB, BT, 0, stream>>>(cls, pred, iminfo,
                                 hist, &barctrl[0], &barctrl[1],
                                 boxes, scores, keys, skeys, sidx,
                                 cboxes, cscores, kpm, sup, out);
}